// Round 5
// baseline (459.935 us; speedup 1.0000x reference)
//
#include <hip/hip_runtime.h>

#define V_TOT 271633
#define NRR 116
#define CIN 1536   // C*D*D*D = 192*8
#define T_LEN 24
#define B_SZ 8
#define NP (NRR*NRR) // 13456
#define CATN 308     // 116 + 192
#define NB1 1062     // ceil(V_TOT/256)
#define WPAD 310

// ---------- xbar[b,i] = mean_t x[b,i,t] ----------
__global__ void xbar_kernel(const float* __restrict__ x, float* __restrict__ xbar) {
    int idx = blockIdx.x * 256 + threadIdx.x;
    if (idx < B_SZ * CIN) {
        const float* p = x + (size_t)idx * T_LEN;
        float s = 0.f;
        #pragma unroll
        for (int t = 0; t < T_LEN; ++t) s += p[t];
        xbar[idx] = s * (1.0f / T_LEN);
    }
}

__device__ __forceinline__ void red4(float4& v) {
    #pragma unroll
    for (int off = 32; off; off >>= 1) {
        v.x += __shfl_xor(v.x, off);
        v.y += __shfl_xor(v.y, off);
        v.z += __shfl_xor(v.z, off);
        v.w += __shfl_xor(v.w, off);
    }
}

#define DOT4(acc, f4, x4) acc += f4.x*x4.x + f4.y*x4.y + f4.z*x4.z + f4.w*x4.w

// ---------- sequential stream of fc_w: per-voxel dot with xbar, in-block
// segment-accumulate by label -> part[block][116][10] (8 dots, fc_b, count) ----------
__global__ __launch_bounds__(256) void fcw_stream_kernel(
        const float* __restrict__ fc_w, const float* __restrict__ fc_b,
        const int* __restrict__ labels, const float* __restrict__ xbar,
        float* __restrict__ part) {
    __shared__ float xb_s[B_SZ * CIN];   // 49152 B
    __shared__ float y8[256][8];         // 8192 B
    __shared__ float fcb_s[256];         // 1024 B
    __shared__ int   lab_s[256];         // 1024 B
    __shared__ float acc[NRR * 10];      // 4640 B   (total 64032 <= 64KB)
    const int tid = threadIdx.x, lane = tid & 63, w = tid >> 6;

    for (int i = tid * 4; i < B_SZ * CIN; i += 1024)
        *(float4*)&xb_s[i] = *(const float4*)&xbar[i];
    for (int i = tid; i < NRR * 10; i += 256) acc[i] = 0.f;
    {
        size_t v = (size_t)blockIdx.x * 256 + tid;
        lab_s[tid] = (v < V_TOT) ? labels[v] : -1;
        fcb_s[tid] = (v < V_TOT) ? fc_b[v] : 0.f;
    }
    __syncthreads();

    // phase 1: 16 iterations, each wave handles 4 consecutive rows
    for (int it = 0; it < 16; ++it) {
        const int r0 = it * 16 + w * 4;
        const size_t vbase = (size_t)blockIdx.x * 256 + r0;
        const float* p0; const float* p1; const float* p2; const float* p3;
        {
            size_t v0 = vbase + 0 < V_TOT ? vbase + 0 : V_TOT - 1;
            size_t v1 = vbase + 1 < V_TOT ? vbase + 1 : V_TOT - 1;
            size_t v2 = vbase + 2 < V_TOT ? vbase + 2 : V_TOT - 1;
            size_t v3 = vbase + 3 < V_TOT ? vbase + 3 : V_TOT - 1;
            p0 = fc_w + v0 * CIN; p1 = fc_w + v1 * CIN;
            p2 = fc_w + v2 * CIN; p3 = fc_w + v3 * CIN;
        }
        float4 dA0{0,0,0,0}, dA1{0,0,0,0}, dA2{0,0,0,0}, dA3{0,0,0,0};
        float4 dB0{0,0,0,0}, dB1{0,0,0,0}, dB2{0,0,0,0}, dB3{0,0,0,0};
        #pragma unroll 2
        for (int j = 0; j < 6; ++j) {
            const int co = j * 256 + lane * 4;
            const float4 f0 = *(const float4*)(p0 + co);
            const float4 f1 = *(const float4*)(p1 + co);
            const float4 f2 = *(const float4*)(p2 + co);
            const float4 f3 = *(const float4*)(p3 + co);
            const float4 x0 = *(const float4*)&xb_s[0*CIN + co];
            const float4 x1 = *(const float4*)&xb_s[1*CIN + co];
            const float4 x2 = *(const float4*)&xb_s[2*CIN + co];
            const float4 x3 = *(const float4*)&xb_s[3*CIN + co];
            const float4 x4 = *(const float4*)&xb_s[4*CIN + co];
            const float4 x5 = *(const float4*)&xb_s[5*CIN + co];
            const float4 x6 = *(const float4*)&xb_s[6*CIN + co];
            const float4 x7 = *(const float4*)&xb_s[7*CIN + co];
            DOT4(dA0.x, f0, x0); DOT4(dA0.y, f0, x1); DOT4(dA0.z, f0, x2); DOT4(dA0.w, f0, x3);
            DOT4(dB0.x, f0, x4); DOT4(dB0.y, f0, x5); DOT4(dB0.z, f0, x6); DOT4(dB0.w, f0, x7);
            DOT4(dA1.x, f1, x0); DOT4(dA1.y, f1, x1); DOT4(dA1.z, f1, x2); DOT4(dA1.w, f1, x3);
            DOT4(dB1.x, f1, x4); DOT4(dB1.y, f1, x5); DOT4(dB1.z, f1, x6); DOT4(dB1.w, f1, x7);
            DOT4(dA2.x, f2, x0); DOT4(dA2.y, f2, x1); DOT4(dA2.z, f2, x2); DOT4(dA2.w, f2, x3);
            DOT4(dB2.x, f2, x4); DOT4(dB2.y, f2, x5); DOT4(dB2.z, f2, x6); DOT4(dB2.w, f2, x7);
            DOT4(dA3.x, f3, x0); DOT4(dA3.y, f3, x1); DOT4(dA3.z, f3, x2); DOT4(dA3.w, f3, x3);
            DOT4(dB3.x, f3, x4); DOT4(dB3.y, f3, x5); DOT4(dB3.z, f3, x6); DOT4(dB3.w, f3, x7);
        }
        red4(dA0); red4(dB0); red4(dA1); red4(dB1);
        red4(dA2); red4(dB2); red4(dA3); red4(dB3);
        if (lane == 0) {
            *(float4*)&y8[r0+0][0] = dA0; *(float4*)&y8[r0+0][4] = dB0;
            *(float4*)&y8[r0+1][0] = dA1; *(float4*)&y8[r0+1][4] = dB1;
            *(float4*)&y8[r0+2][0] = dA2; *(float4*)&y8[r0+2][4] = dB2;
            *(float4*)&y8[r0+3][0] = dA3; *(float4*)&y8[r0+3][4] = dB3;
        }
    }
    __syncthreads();

    // phase 2: wave w owns columns c = w, w+4, w+8 (disjoint -> deterministic)
    for (int c = w; c < 10; c += 4) {
        #pragma unroll
        for (int base = 0; base < 256; base += 64) {
            const int i = base + lane;
            const int r = lab_s[i];
            if (r >= 0) {
                const float val = (c < 8) ? y8[i][c] : ((c == 8) ? fcb_s[i] : 1.0f);
                atomicAdd(&acc[r * 10 + c], val);
            }
        }
    }
    __syncthreads();
    float* po = part + (size_t)blockIdx.x * (NRR * 10);
    for (int i = tid; i < NRR * 10; i += 256) po[i] = acc[i];
}

// ---------- x_node[b][r] = (dotsum[b] + fcbsum) / count ----------
__global__ __launch_bounds__(256) void finalize_kernel(const float* __restrict__ part,
                                                       float* __restrict__ x_node) {
    const int r = blockIdx.x;
    const int lane = threadIdx.x & 63, w = threadIdx.x >> 6;
    float s[10] = {0,0,0,0,0,0,0,0,0,0};
    for (int i = threadIdx.x; i < NB1; i += 256) {
        const float* p = part + (size_t)i * (NRR * 10) + r * 10;
        #pragma unroll
        for (int c = 0; c < 10; ++c) s[c] += p[c];
    }
    __shared__ float red[4][10];
    #pragma unroll
    for (int c = 0; c < 10; ++c) {
        float v = s[c];
        for (int off = 32; off; off >>= 1) v += __shfl_down(v, off);
        if (lane == 0) red[w][c] = v;
    }
    __syncthreads();
    if (threadIdx.x == 0) {
        float t[10];
        #pragma unroll
        for (int c = 0; c < 10; ++c) t[c] = red[0][c] + red[1][c] + red[2][c] + red[3][c];
        const float inv = 1.0f / t[9];
        #pragma unroll
        for (int b = 0; b < B_SZ; ++b) x_node[b * NRR + r] = (t[b] + t[8]) * inv;
    }
}

// ---------- per-ROI tiny MLPs: one wave per (b, r) ----------
__global__ void fs_mlp_kernel(const float* __restrict__ x_node,
                              const float* __restrict__ w1, const float* __restrict__ b1,
                              const float* __restrict__ w2, const float* __restrict__ b2,
                              const float* __restrict__ w3, const float* __restrict__ b3,
                              float* __restrict__ fx) {
    int w = blockIdx.x * 4 + (threadIdx.x >> 6);
    int lane = threadIdx.x & 63;
    int b = w / NRR, r = w % NRR;
    float xn = x_node[b * NRR + r];
    float h1 = fmaxf(xn * w1[r*64 + lane] + b1[r*64 + lane], 0.f);
    const float* w2row = w2 + ((size_t)r*64 + lane) * 64;
    float acc = b2[r*64 + lane];
    #pragma unroll
    for (int i = 0; i < 64; ++i) acc += __shfl(h1, i) * w2row[i];
    float h2 = fmaxf(acc, 0.f);
    float p = h2 * w3[r*64 + lane];
    for (int s = 32; s > 0; s >>= 1) p += __shfl_down(p, s);
    if (lane == 0) fx[b * NRR + r] = p + b3[r];
}

// ---------- distance MLP: one wave per pair p ----------
__global__ void dist_mlp_kernel(const float* __restrict__ dist,
                                const float* __restrict__ mw1, const float* __restrict__ mb1,
                                const float* __restrict__ mw2, const float* __restrict__ mb2,
                                const float* __restrict__ mw3, const float* __restrict__ mb3,
                                float* __restrict__ md) {
    int p = blockIdx.x * 4 + (threadIdx.x >> 6);
    int lane = threadIdx.x & 63;
    float d = dist[p];
    float g1 = fmaxf(d * mw1[lane] + mb1[lane], 0.f);
    const float* w2row = mw2 + lane * 64;
    float acc = mb2[lane];
    #pragma unroll
    for (int i = 0; i < 64; ++i) acc += __shfl(g1, i) * w2row[i];
    float g2 = fmaxf(acc, 0.f);
    float t = g2 * mw3[lane];
    for (int s = 32; s > 0; s >>= 1) t += __shfl_down(t, s);
    if (lane == 0) md[p] = t + mb3[0];
}

// ---------- fc1 partials: grid (64,4) -> mmatpart[j][q] ----------
__global__ __launch_bounds__(256) void fc1_kernel(const float* __restrict__ fc1_w,
                                                  const float* __restrict__ md,
                                                  float* __restrict__ mmatpart) {
    const int j = blockIdx.x, q = blockIdx.y;
    const int p0 = q * (NP/4), p1 = p0 + (NP/4);
    const float* row = fc1_w + (size_t)j * NP;
    float s = 0.f;
    for (int p = p0 + threadIdx.x; p < p1; p += 256) s += row[p] * md[p];
    __shared__ float red[4];
    for (int sft = 32; sft > 0; sft >>= 1) s += __shfl_down(s, sft);
    if ((threadIdx.x & 63) == 0) red[threadIdx.x >> 6] = s;
    __syncthreads();
    if (threadIdx.x == 0) mmatpart[j*4 + q] = red[0] + red[1] + red[2] + red[3];
}

// ---------- weff partials: grid (2,8) -> weffpart[jb][310] ----------
__global__ __launch_bounds__(256) void weff_kernel(const float* __restrict__ hidden_w,
                                                   const float* __restrict__ hidden_b,
                                                   const float* __restrict__ out_w,
                                                   const float* __restrict__ out_b,
                                                   float* __restrict__ weffpart) {
    const int k = blockIdx.x * 256 + threadIdx.x;
    const int jb = blockIdx.y;
    const int j0 = jb * 96, j1 = j0 + 96;
    if (k < CATN) {
        float s = 0.f;
        for (int j = j0; j < j1; ++j) s += hidden_w[(size_t)j * CATN + k] * out_w[j];
        weffpart[jb*WPAD + k] = s;
    } else if (k == CATN) {
        float s = 0.f;
        for (int j = j0; j < j1; ++j) s += hidden_b[j] * out_w[j];
        weffpart[jb*WPAD + CATN] = s + (jb == 0 ? out_b[0] : 0.f);
    }
}

// ---------- fused tail: mmat combine + cat + out. 1 block, 512 threads ----------
__global__ __launch_bounds__(512) void tail_kernel(const float* __restrict__ mmatpart,
                                                   const float* __restrict__ fc1_b,
                                                   const float* __restrict__ fx,
                                                   const float* __restrict__ xbar,
                                                   const float* __restrict__ weffpart,
                                                   float* __restrict__ out) {
    __shared__ float mmat[64];
    __shared__ float cat[B_SZ][CATN];
    if (threadIdx.x < 64) {
        const float* p = mmatpart + threadIdx.x*4;
        mmat[threadIdx.x] = p[0] + p[1] + p[2] + p[3] + fc1_b[threadIdx.x];
    }
    __syncthreads();
    for (int idx = threadIdx.x; idx < B_SZ * NRR; idx += 512) {
        int b = idx / NRR, r = idx % NRR;
        float s = 0.f;
        #pragma unroll
        for (int kk = 0; kk < 8; ++kk) s += mmat[b*8 + kk] * fx[kk * NRR + r];
        cat[b][r] = s;
    }
    for (int idx = threadIdx.x; idx < B_SZ * 192; idx += 512) {
        int b = idx / 192, c = idx % 192;
        float s = 0.f;
        #pragma unroll
        for (int j = 0; j < 8; ++j) s += xbar[b * CIN + c*8 + j];
        cat[b][NRR + c] = s * (1.0f / 8.0f);
    }
    __syncthreads();
    const int b = threadIdx.x >> 6, lane = threadIdx.x & 63;
    float s = 0.f;
    for (int k = lane; k < CATN; k += 64) {
        float wk = 0.f;
        #pragma unroll
        for (int jb = 0; jb < 8; ++jb) wk += weffpart[jb*WPAD + k];
        s += cat[b][k] * wk;
    }
    for (int sft = 32; sft > 0; sft >>= 1) s += __shfl_down(s, sft);
    if (lane == 0) {
        float beff = 0.f;
        #pragma unroll
        for (int jb = 0; jb < 8; ++jb) beff += weffpart[jb*WPAD + CATN];
        out[b] = s + beff;
    }
}

extern "C" void kernel_launch(void* const* d_in, const int* in_sizes, int n_in,
                              void* d_out, int out_size, void* d_ws, size_t ws_size,
                              hipStream_t stream) {
    const float* x        = (const float*)d_in[0];
    const int*   labels   = (const int*)d_in[1];
    const float* dist     = (const float*)d_in[2];
    const float* fc_w     = (const float*)d_in[3];
    const float* fc_b     = (const float*)d_in[4];
    const float* fs_w1    = (const float*)d_in[5];
    const float* fs_b1    = (const float*)d_in[6];
    const float* fs_w2    = (const float*)d_in[7];
    const float* fs_b2    = (const float*)d_in[8];
    const float* fs_w3    = (const float*)d_in[9];
    const float* fs_b3    = (const float*)d_in[10];
    const float* m_w1     = (const float*)d_in[11];
    const float* m_b1     = (const float*)d_in[12];
    const float* m_w2     = (const float*)d_in[13];
    const float* m_b2     = (const float*)d_in[14];
    const float* m_w3     = (const float*)d_in[15];
    const float* m_b3     = (const float*)d_in[16];
    const float* fc1_w    = (const float*)d_in[17];
    const float* fc1_b    = (const float*)d_in[18];
    const float* hidden_w = (const float*)d_in[19];
    const float* hidden_b = (const float*)d_in[20];
    const float* out_w    = (const float*)d_in[21];
    const float* out_b    = (const float*)d_in[22];
    float* out = (float*)d_out;

    // workspace layout (floats)
    float* fb = (float*)d_ws;
    float* part     = fb;  fb += (size_t)NB1 * NRR * 10;   // ~4.93 MB
    float* xbar     = fb;  fb += B_SZ * CIN;
    float* x_node   = fb;  fb += B_SZ * NRR + 32;
    float* fx       = fb;  fb += B_SZ * NRR + 32;
    float* md       = fb;  fb += NP;
    float* mmatpart = fb;  fb += 256;
    float* weffpart = fb;  fb += 8 * WPAD;

    xbar_kernel<<<(B_SZ * CIN + 255) / 256, 256, 0, stream>>>(x, xbar);
    fcw_stream_kernel<<<NB1, 256, 0, stream>>>(fc_w, fc_b, labels, xbar, part);
    dist_mlp_kernel<<<NP / 4, 256, 0, stream>>>(dist, m_w1, m_b1, m_w2, m_b2, m_w3, m_b3, md);
    fc1_kernel<<<dim3(64, 4), 256, 0, stream>>>(fc1_w, md, mmatpart);
    weff_kernel<<<dim3(2, 8), 256, 0, stream>>>(hidden_w, hidden_b, out_w, out_b, weffpart);
    finalize_kernel<<<NRR, 256, 0, stream>>>(part, x_node);
    fs_mlp_kernel<<<232, 256, 0, stream>>>(x_node, fs_w1, fs_b1, fs_w2, fs_b2, fs_w3, fs_b3, fx);
    tail_kernel<<<1, 512, 0, stream>>>(mmatpart, fc1_b, fx, xbar, weffpart, out);
}

// Round 7
// 348.762 us; speedup vs baseline: 1.3188x; 1.3188x over previous
//
#include <hip/hip_runtime.h>

#define V_TOT 271633
#define NRR 116
#define CIN 1536   // C*D*D*D = 192*8
#define T_LEN 24
#define B_SZ 8
#define NP (NRR*NRR) // 13456
#define CATN 308     // 116 + 192
#define SPLITS 44
#define VB 1062      // ceil(V_TOT/256)
#define WPAD 310
#define DPS 12       // dotpart stride: 8 dots + fc_b partial + pad

typedef float nfloat4 __attribute__((ext_vector_type(4)));

// ---------- merged: blocks [0,VB) histogram labels; blocks [VB,VB+48) xbar ----------
__global__ __launch_bounds__(256) void hist_xbar_kernel(const int* __restrict__ labels,
                                                        int* __restrict__ blockHist,
                                                        const float* __restrict__ x,
                                                        float* __restrict__ xbar) {
    if (blockIdx.x < VB) {
        __shared__ int h[NRR];
        for (int i = threadIdx.x; i < NRR; i += 256) h[i] = 0;
        __syncthreads();
        int v = blockIdx.x * 256 + threadIdx.x;
        if (v < V_TOT) atomicAdd(&h[labels[v]], 1);
        __syncthreads();
        for (int i = threadIdx.x; i < NRR; i += 256)
            blockHist[(size_t)i * VB + blockIdx.x] = h[i];
    } else {
        int idx = (blockIdx.x - VB) * 256 + threadIdx.x;
        if (idx < B_SZ * CIN) {
            const float* p = x + (size_t)idx * T_LEN;
            float s = 0.f;
            #pragma unroll
            for (int t = 0; t < T_LEN; ++t) s += p[t];
            xbar[idx] = s * (1.0f / T_LEN);
        }
    }
}

__global__ __launch_bounds__(256) void binscan_kernel(const int* __restrict__ blockHist,
                                                      int* __restrict__ blockBase,
                                                      int* __restrict__ counts) {
    const int r = blockIdx.x;
    const int lane = threadIdx.x & 63, w = threadIdx.x >> 6;
    __shared__ int wsum[4];
    int run = 0;
    for (int base = 0; base < VB; base += 256) {
        const int i = base + threadIdx.x;
        const int orig = (i < VB) ? blockHist[(size_t)r * VB + i] : 0;
        int val = orig;
        #pragma unroll
        for (int off = 1; off < 64; off <<= 1) {
            int t = __shfl_up(val, off);
            if (lane >= off) val += t;
        }
        if (lane == 63) wsum[w] = val;
        __syncthreads();
        int woff = 0;
        #pragma unroll
        for (int j = 0; j < 4; ++j) if (j < w) woff += wsum[j];
        if (i < VB) blockBase[(size_t)r * VB + i] = run + woff + val - orig;
        int tot = wsum[0] + wsum[1] + wsum[2] + wsum[3];
        __syncthreads();
        run += tot;
    }
    if (threadIdx.x == 0) counts[r] = run;
}

__global__ void offsets_kernel(const int* __restrict__ counts, int* __restrict__ offsets) {
    if (threadIdx.x == 0) {
        int acc = 0;
        for (int r = 0; r < NRR; ++r) { offsets[r] = acc; acc += counts[r]; }
        offsets[NRR] = acc;
    }
}

__global__ __launch_bounds__(256) void scatter_kernel(const int* __restrict__ labels,
                                                      const int* __restrict__ offsets,
                                                      const int* __restrict__ blockBase,
                                                      int* __restrict__ perm) {
    __shared__ int lab[256];
    const int v = blockIdx.x * 256 + threadIdx.x;
    const int r = (v < V_TOT) ? labels[v] : -1;
    lab[threadIdx.x] = r;
    __syncthreads();
    if (r >= 0) {
        int rank = 0;
        for (int t = 0; t < (int)threadIdx.x; ++t) rank += (lab[t] == r);
        perm[offsets[r] + blockBase[(size_t)r * VB + blockIdx.x] + rank] = v;
    }
}

__device__ __forceinline__ void add4(float4& a, const float4 b) {
    a.x += b.x; a.y += b.y; a.z += b.z; a.w += b.w;
}
__device__ __forceinline__ float4 ldnt4(const float* p) {
    nfloat4 v = __builtin_nontemporal_load((const nfloat4*)p);
    return make_float4(v.x, v.y, v.z, v.w);
}

// ---------- fused partial row-sum of fc_w + dot with xbar + fc_b partial ----------
// grid (116, 44), block 384 = 6 waves. launch_bounds(384,6): ~4 blocks/CU.
__global__ __launch_bounds__(384, 6) void roi_partial_dot_kernel(
        const float* __restrict__ fc_w, const float* __restrict__ fc_b,
        const int* __restrict__ perm,
        const int* __restrict__ counts, const int* __restrict__ offsets,
        const float* __restrict__ xbar, float* __restrict__ dotpart) {
    const int r = blockIdx.x, s = blockIdx.y;
    const int n = counts[r], off = offsets[r];
    const int chunk = (n + SPLITS - 1) / SPLITS;
    const int k0 = min(s * chunk, n);
    const int k1 = min(k0 + chunk, n);
    const int c4 = threadIdx.x * 4;

    float4 a0{0,0,0,0}, a1{0,0,0,0}, a2{0,0,0,0}, a3{0,0,0,0};
    float4 a4{0,0,0,0}, a5{0,0,0,0}, a6{0,0,0,0}, a7{0,0,0,0};
    int k = k0;
    for (; k + 8 <= k1; k += 8) {
        const int v0 = perm[off+k+0], v1 = perm[off+k+1], v2 = perm[off+k+2], v3 = perm[off+k+3];
        const int v4 = perm[off+k+4], v5 = perm[off+k+5], v6 = perm[off+k+6], v7 = perm[off+k+7];
        const float4 x0 = ldnt4(fc_w + (size_t)v0*CIN + c4);
        const float4 x1 = ldnt4(fc_w + (size_t)v1*CIN + c4);
        const float4 x2 = ldnt4(fc_w + (size_t)v2*CIN + c4);
        const float4 x3 = ldnt4(fc_w + (size_t)v3*CIN + c4);
        const float4 x4 = ldnt4(fc_w + (size_t)v4*CIN + c4);
        const float4 x5 = ldnt4(fc_w + (size_t)v5*CIN + c4);
        const float4 x6 = ldnt4(fc_w + (size_t)v6*CIN + c4);
        const float4 x7 = ldnt4(fc_w + (size_t)v7*CIN + c4);
        add4(a0, x0); add4(a1, x1); add4(a2, x2); add4(a3, x3);
        add4(a4, x4); add4(a5, x5); add4(a6, x6); add4(a7, x7);
    }
    for (; k < k1; ++k) {
        const int v = perm[off+k];
        add4(a0, ldnt4(fc_w + (size_t)v*CIN + c4));
    }
    add4(a0, a1); add4(a2, a3); add4(a4, a5); add4(a6, a7);
    add4(a0, a2); add4(a4, a6); add4(a0, a4);

    // fc_b partial over this chunk
    float bacc = 0.f;
    for (int kk = k0 + threadIdx.x; kk < k1; kk += 384) bacc += fc_b[perm[off+kk]];

    // dot partial row-sum (a0 = cols c4..c4+3) with xbar[b]
    float d[B_SZ];
    #pragma unroll
    for (int b = 0; b < B_SZ; ++b) {
        const float4 xb = *(const float4*)(xbar + b*CIN + c4);
        d[b] = a0.x*xb.x + a0.y*xb.y + a0.z*xb.z + a0.w*xb.w;
    }
    __shared__ float red[6][9];
    const int lane = threadIdx.x & 63, w = threadIdx.x >> 6;
    #pragma unroll
    for (int b = 0; b < B_SZ; ++b) {
        float v = d[b];
        for (int sft = 32; sft > 0; sft >>= 1) v += __shfl_down(v, sft);
        if (lane == 0) red[w][b] = v;
    }
    {
        float v = bacc;
        for (int sft = 32; sft > 0; sft >>= 1) v += __shfl_down(v, sft);
        if (lane == 0) red[w][8] = v;
    }
    __syncthreads();
    if (threadIdx.x < 9) {
        float v = 0.f;
        #pragma unroll
        for (int j = 0; j < 6; ++j) v += red[j][threadIdx.x];
        dotpart[((size_t)(r*SPLITS + s))*DPS + threadIdx.x] = v;
    }
}

// ---------- fused x_node finalize + per-ROI tiny MLPs: one wave per (b,r) ----------
__global__ void fs_mlp_kernel(const float* __restrict__ dotpart, const int* __restrict__ counts,
                              const float* __restrict__ w1, const float* __restrict__ b1,
                              const float* __restrict__ w2, const float* __restrict__ b2,
                              const float* __restrict__ w3, const float* __restrict__ b3,
                              float* __restrict__ fx) {
    int w = blockIdx.x * 4 + (threadIdx.x >> 6);
    int lane = threadIdx.x & 63;
    int b = w / NRR, r = w % NRR;
    // x_node = (sum_s dotpart[r][s][b] + sum_s dotpart[r][s][8]) / n
    float sdot = 0.f, sb = 0.f;
    if (lane < SPLITS) {
        const float* p = dotpart + ((size_t)(r*SPLITS + lane))*DPS;
        sdot = p[b]; sb = p[8];
    }
    #pragma unroll
    for (int off = 32; off > 0; off >>= 1) {
        sdot += __shfl_xor(sdot, off);
        sb   += __shfl_xor(sb, off);
    }
    float xn = (sdot + sb) / (float)counts[r];

    float h1 = fmaxf(xn * w1[r*64 + lane] + b1[r*64 + lane], 0.f);
    const float* w2row = w2 + ((size_t)r*64 + lane) * 64;
    float acc = b2[r*64 + lane];
    #pragma unroll
    for (int i = 0; i < 64; ++i) acc += __shfl(h1, i) * w2row[i];
    float h2 = fmaxf(acc, 0.f);
    float p = h2 * w3[r*64 + lane];
    for (int sft = 32; sft > 0; sft >>= 1) p += __shfl_down(p, sft);
    if (lane == 0) fx[b * NRR + r] = p + b3[r];
}

// ---------- distance MLP: one wave per pair p ----------
__global__ void dist_mlp_kernel(const float* __restrict__ dist,
                                const float* __restrict__ mw1, const float* __restrict__ mb1,
                                const float* __restrict__ mw2, const float* __restrict__ mb2,
                                const float* __restrict__ mw3, const float* __restrict__ mb3,
                                float* __restrict__ md) {
    int p = blockIdx.x * 4 + (threadIdx.x >> 6);
    int lane = threadIdx.x & 63;
    float d = dist[p];
    float g1 = fmaxf(d * mw1[lane] + mb1[lane], 0.f);
    const float* w2row = mw2 + lane * 64;
    float acc = mb2[lane];
    #pragma unroll
    for (int i = 0; i < 64; ++i) acc += __shfl(g1, i) * w2row[i];
    float g2 = fmaxf(acc, 0.f);
    float t = g2 * mw3[lane];
    for (int s = 32; s > 0; s >>= 1) t += __shfl_down(t, s);
    if (lane == 0) md[p] = t + mb3[0];
}

// ---------- fc1 partials: grid (64,4) -> mmatpart[j][q] ----------
__global__ __launch_bounds__(256) void fc1_kernel(const float* __restrict__ fc1_w,
                                                  const float* __restrict__ md,
                                                  float* __restrict__ mmatpart) {
    const int j = blockIdx.x, q = blockIdx.y;
    const int p0 = q * (NP/4), p1 = p0 + (NP/4);
    const float* row = fc1_w + (size_t)j * NP;
    float s = 0.f;
    for (int p = p0 + threadIdx.x; p < p1; p += 256) s += row[p] * md[p];
    __shared__ float red[4];
    for (int sft = 32; sft > 0; sft >>= 1) s += __shfl_down(s, sft);
    if ((threadIdx.x & 63) == 0) red[threadIdx.x >> 6] = s;
    __syncthreads();
    if (threadIdx.x == 0) mmatpart[j*4 + q] = red[0] + red[1] + red[2] + red[3];
}

// ---------- weff partials: grid (2,8) -> weffpart[jb][310] ----------
__global__ __launch_bounds__(256) void weff_kernel(const float* __restrict__ hidden_w,
                                                   const float* __restrict__ hidden_b,
                                                   const float* __restrict__ out_w,
                                                   const float* __restrict__ out_b,
                                                   float* __restrict__ weffpart) {
    const int k = blockIdx.x * 256 + threadIdx.x;
    const int jb = blockIdx.y;
    const int j0 = jb * 96, j1 = j0 + 96;
    if (k < CATN) {
        float s = 0.f;
        for (int j = j0; j < j1; ++j) s += hidden_w[(size_t)j * CATN + k] * out_w[j];
        weffpart[jb*WPAD + k] = s;
    } else if (k == CATN) {
        float s = 0.f;
        for (int j = j0; j < j1; ++j) s += hidden_b[j] * out_w[j];
        weffpart[jb*WPAD + CATN] = s + (jb == 0 ? out_b[0] : 0.f);
    }
}

// ---------- fused tail: mmat combine + cat + out. 1 block, 512 threads ----------
__global__ __launch_bounds__(512) void tail_kernel(const float* __restrict__ mmatpart,
                                                   const float* __restrict__ fc1_b,
                                                   const float* __restrict__ fx,
                                                   const float* __restrict__ xbar,
                                                   const float* __restrict__ weffpart,
                                                   float* __restrict__ out) {
    __shared__ float mmat[64];
    __shared__ float cat[B_SZ][CATN];
    if (threadIdx.x < 64) {
        const float* p = mmatpart + threadIdx.x*4;
        mmat[threadIdx.x] = p[0] + p[1] + p[2] + p[3] + fc1_b[threadIdx.x];
    }
    __syncthreads();
    for (int idx = threadIdx.x; idx < B_SZ * NRR; idx += 512) {
        int b = idx / NRR, r = idx % NRR;
        float s = 0.f;
        #pragma unroll
        for (int kk = 0; kk < 8; ++kk) s += mmat[b*8 + kk] * fx[kk * NRR + r];
        cat[b][r] = s;
    }
    for (int idx = threadIdx.x; idx < B_SZ * 192; idx += 512) {
        int b = idx / 192, c = idx % 192;
        float s = 0.f;
        #pragma unroll
        for (int j = 0; j < 8; ++j) s += xbar[b * CIN + c*8 + j];
        cat[b][NRR + c] = s * (1.0f / 8.0f);
    }
    __syncthreads();
    const int b = threadIdx.x >> 6, lane = threadIdx.x & 63;
    float s = 0.f;
    for (int k = lane; k < CATN; k += 64) {
        float wk = 0.f;
        #pragma unroll
        for (int jb = 0; jb < 8; ++jb) wk += weffpart[jb*WPAD + k];
        s += cat[b][k] * wk;
    }
    for (int sft = 32; sft > 0; sft >>= 1) s += __shfl_down(s, sft);
    if (lane == 0) {
        float beff = 0.f;
        #pragma unroll
        for (int jb = 0; jb < 8; ++jb) beff += weffpart[jb*WPAD + CATN];
        out[b] = s + beff;
    }
}

extern "C" void kernel_launch(void* const* d_in, const int* in_sizes, int n_in,
                              void* d_out, int out_size, void* d_ws, size_t ws_size,
                              hipStream_t stream) {
    const float* x        = (const float*)d_in[0];
    const int*   labels   = (const int*)d_in[1];
    const float* dist     = (const float*)d_in[2];
    const float* fc_w     = (const float*)d_in[3];
    const float* fc_b     = (const float*)d_in[4];
    const float* fs_w1    = (const float*)d_in[5];
    const float* fs_b1    = (const float*)d_in[6];
    const float* fs_w2    = (const float*)d_in[7];
    const float* fs_b2    = (const float*)d_in[8];
    const float* fs_w3    = (const float*)d_in[9];
    const float* fs_b3    = (const float*)d_in[10];
    const float* m_w1     = (const float*)d_in[11];
    const float* m_b1     = (const float*)d_in[12];
    const float* m_w2     = (const float*)d_in[13];
    const float* m_b2     = (const float*)d_in[14];
    const float* m_w3     = (const float*)d_in[15];
    const float* m_b3     = (const float*)d_in[16];
    const float* fc1_w    = (const float*)d_in[17];
    const float* fc1_b    = (const float*)d_in[18];
    const float* hidden_w = (const float*)d_in[19];
    const float* hidden_b = (const float*)d_in[20];
    const float* out_w    = (const float*)d_in[21];
    const float* out_b    = (const float*)d_in[22];
    float* out = (float*)d_out;

    // workspace layout
    int* counts    = (int*)d_ws;               // 128
    int* offsets   = counts + 128;             // 128
    int* blockHist = offsets + 128;            // NRR*VB
    int* blockBase = blockHist + NRR*VB;       // NRR*VB
    int* perm      = blockBase + NRR*VB;       // V_TOT
    float* fb = (float*)(perm + ((V_TOT + 255) / 256) * 256);
    float* dotpart  = fb;  fb += (size_t)NRR * SPLITS * DPS;  // 61248
    float* xbar     = fb;  fb += B_SZ * CIN;
    float* fx       = fb;  fb += B_SZ * NRR + 32;
    float* md       = fb;  fb += NP;
    float* mmatpart = fb;  fb += 256;
    float* weffpart = fb;  fb += 8 * WPAD;

    hist_xbar_kernel<<<VB + 48, 256, 0, stream>>>(labels, blockHist, x, xbar);
    binscan_kernel<<<NRR, 256, 0, stream>>>(blockHist, blockBase, counts);
    offsets_kernel<<<1, 64, 0, stream>>>(counts, offsets);
    scatter_kernel<<<VB, 256, 0, stream>>>(labels, offsets, blockBase, perm);
    roi_partial_dot_kernel<<<dim3(NRR, SPLITS), 384, 0, stream>>>(fc_w, fc_b, perm, counts, offsets, xbar, dotpart);
    dist_mlp_kernel<<<NP / 4, 256, 0, stream>>>(dist, m_w1, m_b1, m_w2, m_b2, m_w3, m_b3, md);
    fc1_kernel<<<dim3(64, 4), 256, 0, stream>>>(fc1_w, md, mmatpart);
    weff_kernel<<<dim3(2, 8), 256, 0, stream>>>(hidden_w, hidden_b, out_w, out_b, weffpart);
    fs_mlp_kernel<<<232, 256, 0, stream>>>(dotpart, counts, fs_w1, fs_b1, fs_w2, fs_b2, fs_w3, fs_b3, fx);
    tail_kernel<<<1, 512, 0, stream>>>(mmatpart, fc1_b, fx, xbar, weffpart, out);
}

// Round 8
// 324.454 us; speedup vs baseline: 1.4176x; 1.0749x over previous
//
#include <hip/hip_runtime.h>

#define V_TOT 271633
#define NRR 116
#define CIN 1536   // C*D*D*D = 192*8
#define T_LEN 24
#define B_SZ 8
#define NP (NRR*NRR) // 13456
#define CATN 308     // 116 + 192
#define SPLITS 44
#define NST (NRR*SPLITS)  // 5104
#define VB 1062      // ceil(V_TOT/256)
#define WPAD 310
#define DPS 12       // dotpart stride: 8 dots + fc_b partial + pad
#define DISTB 2243   // ceil(13456/6)
#define MEGA_STREAM_BASE (DISTB + 8)

typedef float nfloat4 __attribute__((ext_vector_type(4)));

// ---------- merged: blocks [0,VB) histogram labels; blocks [VB,VB+48) xbar ----------
__global__ __launch_bounds__(256) void hist_xbar_kernel(const int* __restrict__ labels,
                                                        int* __restrict__ blockHist,
                                                        const float* __restrict__ x,
                                                        float* __restrict__ xbar) {
    if (blockIdx.x < VB) {
        __shared__ int h[NRR];
        for (int i = threadIdx.x; i < NRR; i += 256) h[i] = 0;
        __syncthreads();
        int v = blockIdx.x * 256 + threadIdx.x;
        if (v < V_TOT) atomicAdd(&h[labels[v]], 1);
        __syncthreads();
        for (int i = threadIdx.x; i < NRR; i += 256)
            blockHist[(size_t)i * VB + blockIdx.x] = h[i];
    } else {
        int idx = (blockIdx.x - VB) * 256 + threadIdx.x;
        if (idx < B_SZ * CIN) {
            const float* p = x + (size_t)idx * T_LEN;
            float s = 0.f;
            #pragma unroll
            for (int t = 0; t < T_LEN; ++t) s += p[t];
            xbar[idx] = s * (1.0f / T_LEN);
        }
    }
}

__global__ __launch_bounds__(256) void binscan_kernel(const int* __restrict__ blockHist,
                                                      int* __restrict__ blockBase,
                                                      int* __restrict__ counts) {
    const int r = blockIdx.x;
    const int lane = threadIdx.x & 63, w = threadIdx.x >> 6;
    __shared__ int wsum[4];
    int run = 0;
    for (int base = 0; base < VB; base += 256) {
        const int i = base + threadIdx.x;
        const int orig = (i < VB) ? blockHist[(size_t)r * VB + i] : 0;
        int val = orig;
        #pragma unroll
        for (int off = 1; off < 64; off <<= 1) {
            int t = __shfl_up(val, off);
            if (lane >= off) val += t;
        }
        if (lane == 63) wsum[w] = val;
        __syncthreads();
        int woff = 0;
        #pragma unroll
        for (int j = 0; j < 4; ++j) if (j < w) woff += wsum[j];
        if (i < VB) blockBase[(size_t)r * VB + i] = run + woff + val - orig;
        int tot = wsum[0] + wsum[1] + wsum[2] + wsum[3];
        __syncthreads();
        run += tot;
    }
    if (threadIdx.x == 0) counts[r] = run;
}

__global__ void offsets_kernel(const int* __restrict__ counts, int* __restrict__ offsets) {
    if (threadIdx.x == 0) {
        int acc = 0;
        for (int r = 0; r < NRR; ++r) { offsets[r] = acc; acc += counts[r]; }
        offsets[NRR] = acc;
    }
}

__global__ __launch_bounds__(256) void scatter_kernel(const int* __restrict__ labels,
                                                      const int* __restrict__ offsets,
                                                      const int* __restrict__ blockBase,
                                                      int* __restrict__ perm) {
    __shared__ int lab[256];
    const int v = blockIdx.x * 256 + threadIdx.x;
    const int r = (v < V_TOT) ? labels[v] : -1;
    lab[threadIdx.x] = r;
    __syncthreads();
    if (r >= 0) {
        int rank = 0;
        for (int t = 0; t < (int)threadIdx.x; ++t) rank += (lab[t] == r);
        perm[offsets[r] + blockBase[(size_t)r * VB + blockIdx.x] + rank] = v;
    }
}

__device__ __forceinline__ void add4(float4& a, const float4 b) {
    a.x += b.x; a.y += b.y; a.z += b.z; a.w += b.w;
}
__device__ __forceinline__ float4 ldnt4(const float* p) {
    nfloat4 v = __builtin_nontemporal_load((const nfloat4*)p);
    return make_float4(v.x, v.y, v.z, v.w);
}

// ---------- MEGA: [0,DISTB) dist_mlp, [DISTB,DISTB+8) weff, rest roi_partial_dot ----------
__global__ __launch_bounds__(384, 6) void mega_kernel(
        const float* __restrict__ fc_w, const float* __restrict__ fc_b,
        const int* __restrict__ perm,
        const int* __restrict__ counts, const int* __restrict__ offsets,
        const float* __restrict__ xbar, float* __restrict__ dotpart,
        const float* __restrict__ dist,
        const float* __restrict__ mw1, const float* __restrict__ mb1,
        const float* __restrict__ mw2, const float* __restrict__ mb2,
        const float* __restrict__ mw3, const float* __restrict__ mb3,
        float* __restrict__ md,
        const float* __restrict__ hidden_w, const float* __restrict__ hidden_b,
        const float* __restrict__ out_w, const float* __restrict__ out_b,
        float* __restrict__ weffpart) {
    const int bid = blockIdx.x;
    const int lane = threadIdx.x & 63, w = threadIdx.x >> 6;

    if (bid < DISTB) {
        // ---- distance MLP: 6 waves/block, one pair per wave ----
        const int p = bid * 6 + w;
        if (p < NP) {
            float d = dist[p];
            float g1 = fmaxf(d * mw1[lane] + mb1[lane], 0.f);
            const float* w2row = mw2 + lane * 64;
            float acc = mb2[lane];
            #pragma unroll
            for (int i = 0; i < 64; ++i) acc += __shfl(g1, i) * w2row[i];
            float g2 = fmaxf(acc, 0.f);
            float t = g2 * mw3[lane];
            for (int s = 32; s > 0; s >>= 1) t += __shfl_down(t, s);
            if (lane == 0) md[p] = t + mb3[0];
        }
        return;
    }
    if (bid < MEGA_STREAM_BASE) {
        // ---- weff partials: jb = bid - DISTB ----
        const int jb = bid - DISTB;
        const int k = threadIdx.x;
        const int j0 = jb * 96, j1 = j0 + 96;
        if (k < CATN) {
            float s = 0.f;
            for (int j = j0; j < j1; ++j) s += hidden_w[(size_t)j * CATN + k] * out_w[j];
            weffpart[jb*WPAD + k] = s;
        } else if (k == CATN) {
            float s = 0.f;
            for (int j = j0; j < j1; ++j) s += hidden_b[j] * out_w[j];
            weffpart[jb*WPAD + CATN] = s + (jb == 0 ? out_b[0] : 0.f);
        }
        return;
    }

    // ---- roi_partial_dot ----
    const int sbid = bid - MEGA_STREAM_BASE;
    const int r = sbid / SPLITS, s = sbid % SPLITS;
    const int n = counts[r], off = offsets[r];
    const int chunk = (n + SPLITS - 1) / SPLITS;
    const int k0 = min(s * chunk, n);
    const int k1 = min(k0 + chunk, n);
    const int c4 = threadIdx.x * 4;

    float4 a0{0,0,0,0}, a1{0,0,0,0}, a2{0,0,0,0}, a3{0,0,0,0};
    float4 a4{0,0,0,0}, a5{0,0,0,0}, a6{0,0,0,0}, a7{0,0,0,0};
    int k = k0;
    for (; k + 8 <= k1; k += 8) {
        const int v0 = perm[off+k+0], v1 = perm[off+k+1], v2 = perm[off+k+2], v3 = perm[off+k+3];
        const int v4 = perm[off+k+4], v5 = perm[off+k+5], v6 = perm[off+k+6], v7 = perm[off+k+7];
        const float4 x0 = ldnt4(fc_w + (size_t)v0*CIN + c4);
        const float4 x1 = ldnt4(fc_w + (size_t)v1*CIN + c4);
        const float4 x2 = ldnt4(fc_w + (size_t)v2*CIN + c4);
        const float4 x3 = ldnt4(fc_w + (size_t)v3*CIN + c4);
        const float4 x4 = ldnt4(fc_w + (size_t)v4*CIN + c4);
        const float4 x5 = ldnt4(fc_w + (size_t)v5*CIN + c4);
        const float4 x6 = ldnt4(fc_w + (size_t)v6*CIN + c4);
        const float4 x7 = ldnt4(fc_w + (size_t)v7*CIN + c4);
        add4(a0, x0); add4(a1, x1); add4(a2, x2); add4(a3, x3);
        add4(a4, x4); add4(a5, x5); add4(a6, x6); add4(a7, x7);
    }
    for (; k < k1; ++k) {
        const int v = perm[off+k];
        add4(a0, ldnt4(fc_w + (size_t)v*CIN + c4));
    }
    add4(a0, a1); add4(a2, a3); add4(a4, a5); add4(a6, a7);
    add4(a0, a2); add4(a4, a6); add4(a0, a4);

    // fc_b partial over this chunk
    float bacc = 0.f;
    for (int kk = k0 + threadIdx.x; kk < k1; kk += 384) bacc += fc_b[perm[off+kk]];

    // dot partial row-sum (a0 = cols c4..c4+3) with xbar[b]
    float d[B_SZ];
    #pragma unroll
    for (int b = 0; b < B_SZ; ++b) {
        const float4 xb = *(const float4*)(xbar + b*CIN + c4);
        d[b] = a0.x*xb.x + a0.y*xb.y + a0.z*xb.z + a0.w*xb.w;
    }
    __shared__ float red[6][9];
    #pragma unroll
    for (int b = 0; b < B_SZ; ++b) {
        float v = d[b];
        for (int sft = 32; sft > 0; sft >>= 1) v += __shfl_down(v, sft);
        if (lane == 0) red[w][b] = v;
    }
    {
        float v = bacc;
        for (int sft = 32; sft > 0; sft >>= 1) v += __shfl_down(v, sft);
        if (lane == 0) red[w][8] = v;
    }
    __syncthreads();
    if (threadIdx.x < 9) {
        float v = 0.f;
        #pragma unroll
        for (int j = 0; j < 6; ++j) v += red[j][threadIdx.x];
        dotpart[((size_t)(r*SPLITS + s))*DPS + threadIdx.x] = v;
    }
}

// ---------- mid: [0,232) fs_mlp (x_node finalize + tiny MLPs), [232,488) fc1 partials ----------
__global__ __launch_bounds__(256) void mid_kernel(
        const float* __restrict__ dotpart, const int* __restrict__ counts,
        const float* __restrict__ w1, const float* __restrict__ b1,
        const float* __restrict__ w2, const float* __restrict__ b2,
        const float* __restrict__ w3, const float* __restrict__ b3,
        float* __restrict__ fx,
        const float* __restrict__ fc1_w, const float* __restrict__ md,
        float* __restrict__ mmatpart) {
    const int bid = blockIdx.x;
    const int lane = threadIdx.x & 63;
    if (bid < 232) {
        int w = bid * 4 + (threadIdx.x >> 6);
        int b = w / NRR, r = w % NRR;
        float sdot = 0.f, sb = 0.f;
        if (lane < SPLITS) {
            const float* p = dotpart + ((size_t)(r*SPLITS + lane))*DPS;
            sdot = p[b]; sb = p[8];
        }
        #pragma unroll
        for (int off = 32; off > 0; off >>= 1) {
            sdot += __shfl_xor(sdot, off);
            sb   += __shfl_xor(sb, off);
        }
        float xn = (sdot + sb) / (float)counts[r];

        float h1 = fmaxf(xn * w1[r*64 + lane] + b1[r*64 + lane], 0.f);
        const float* w2row = w2 + ((size_t)r*64 + lane) * 64;
        float acc = b2[r*64 + lane];
        #pragma unroll
        for (int i = 0; i < 64; ++i) acc += __shfl(h1, i) * w2row[i];
        float h2 = fmaxf(acc, 0.f);
        float p = h2 * w3[r*64 + lane];
        for (int sft = 32; sft > 0; sft >>= 1) p += __shfl_down(p, sft);
        if (lane == 0) fx[b * NRR + r] = p + b3[r];
    } else {
        const int fb = bid - 232;
        const int j = fb >> 2, q = fb & 3;
        const int p0 = q * (NP/4), p1 = p0 + (NP/4);
        const float* row = fc1_w + (size_t)j * NP;
        float s = 0.f;
        for (int p = p0 + threadIdx.x; p < p1; p += 256) s += row[p] * md[p];
        __shared__ float red[4];
        for (int sft = 32; sft > 0; sft >>= 1) s += __shfl_down(s, sft);
        if ((threadIdx.x & 63) == 0) red[threadIdx.x >> 6] = s;
        __syncthreads();
        if (threadIdx.x == 0) mmatpart[j*4 + q] = red[0] + red[1] + red[2] + red[3];
    }
}

// ---------- fused tail: mmat combine + cat + out. 1 block, 512 threads ----------
__global__ __launch_bounds__(512) void tail_kernel(const float* __restrict__ mmatpart,
                                                   const float* __restrict__ fc1_b,
                                                   const float* __restrict__ fx,
                                                   const float* __restrict__ xbar,
                                                   const float* __restrict__ weffpart,
                                                   float* __restrict__ out) {
    __shared__ float mmat[64];
    __shared__ float cat[B_SZ][CATN];
    if (threadIdx.x < 64) {
        const float* p = mmatpart + threadIdx.x*4;
        mmat[threadIdx.x] = p[0] + p[1] + p[2] + p[3] + fc1_b[threadIdx.x];
    }
    __syncthreads();
    for (int idx = threadIdx.x; idx < B_SZ * NRR; idx += 512) {
        int b = idx / NRR, r = idx % NRR;
        float s = 0.f;
        #pragma unroll
        for (int kk = 0; kk < 8; ++kk) s += mmat[b*8 + kk] * fx[kk * NRR + r];
        cat[b][r] = s;
    }
    for (int idx = threadIdx.x; idx < B_SZ * 192; idx += 512) {
        int b = idx / 192, c = idx % 192;
        float s = 0.f;
        #pragma unroll
        for (int j = 0; j < 8; ++j) s += xbar[b * CIN + c*8 + j];
        cat[b][NRR + c] = s * (1.0f / 8.0f);
    }
    __syncthreads();
    const int b = threadIdx.x >> 6, lane = threadIdx.x & 63;
    float s = 0.f;
    for (int k = lane; k < CATN; k += 64) {
        float wk = 0.f;
        #pragma unroll
        for (int jb = 0; jb < 8; ++jb) wk += weffpart[jb*WPAD + k];
        s += cat[b][k] * wk;
    }
    for (int sft = 32; sft > 0; sft >>= 1) s += __shfl_down(s, sft);
    if (lane == 0) {
        float beff = 0.f;
        #pragma unroll
        for (int jb = 0; jb < 8; ++jb) beff += weffpart[jb*WPAD + CATN];
        out[b] = s + beff;
    }
}

extern "C" void kernel_launch(void* const* d_in, const int* in_sizes, int n_in,
                              void* d_out, int out_size, void* d_ws, size_t ws_size,
                              hipStream_t stream) {
    const float* x        = (const float*)d_in[0];
    const int*   labels   = (const int*)d_in[1];
    const float* dist     = (const float*)d_in[2];
    const float* fc_w     = (const float*)d_in[3];
    const float* fc_b     = (const float*)d_in[4];
    const float* fs_w1    = (const float*)d_in[5];
    const float* fs_b1    = (const float*)d_in[6];
    const float* fs_w2    = (const float*)d_in[7];
    const float* fs_b2    = (const float*)d_in[8];
    const float* fs_w3    = (const float*)d_in[9];
    const float* fs_b3    = (const float*)d_in[10];
    const float* m_w1     = (const float*)d_in[11];
    const float* m_b1     = (const float*)d_in[12];
    const float* m_w2     = (const float*)d_in[13];
    const float* m_b2     = (const float*)d_in[14];
    const float* m_w3     = (const float*)d_in[15];
    const float* m_b3     = (const float*)d_in[16];
    const float* fc1_w    = (const float*)d_in[17];
    const float* fc1_b    = (const float*)d_in[18];
    const float* hidden_w = (const float*)d_in[19];
    const float* hidden_b = (const float*)d_in[20];
    const float* out_w    = (const float*)d_in[21];
    const float* out_b    = (const float*)d_in[22];
    float* out = (float*)d_out;

    // workspace layout
    int* counts    = (int*)d_ws;               // 128
    int* offsets   = counts + 128;             // 128
    int* blockHist = offsets + 128;            // NRR*VB
    int* blockBase = blockHist + NRR*VB;       // NRR*VB
    int* perm      = blockBase + NRR*VB;       // V_TOT
    float* fb = (float*)(perm + ((V_TOT + 255) / 256) * 256);
    float* dotpart  = fb;  fb += (size_t)NRR * SPLITS * DPS;  // 61248
    float* xbar     = fb;  fb += B_SZ * CIN;
    float* fx       = fb;  fb += B_SZ * NRR + 32;
    float* md       = fb;  fb += NP;
    float* mmatpart = fb;  fb += 256;
    float* weffpart = fb;  fb += 8 * WPAD;

    hist_xbar_kernel<<<VB + 48, 256, 0, stream>>>(labels, blockHist, x, xbar);
    binscan_kernel<<<NRR, 256, 0, stream>>>(blockHist, blockBase, counts);
    offsets_kernel<<<1, 64, 0, stream>>>(counts, offsets);
    scatter_kernel<<<VB, 256, 0, stream>>>(labels, offsets, blockBase, perm);
    mega_kernel<<<MEGA_STREAM_BASE + NST, 384, 0, stream>>>(
        fc_w, fc_b, perm, counts, offsets, xbar, dotpart,
        dist, m_w1, m_b1, m_w2, m_b2, m_w3, m_b3, md,
        hidden_w, hidden_b, out_w, out_b, weffpart);
    mid_kernel<<<488, 256, 0, stream>>>(dotpart, counts,
        fs_w1, fs_b1, fs_w2, fs_b2, fs_w3, fs_b3, fx, fc1_w, md, mmatpart);
    tail_kernel<<<1, 512, 0, stream>>>(mmatpart, fc1_b, fx, xbar, weffpart, out);
}